// Round 1
// baseline (980.804 us; speedup 1.0000x reference)
//
#include <hip/hip_runtime.h>
#include <hip/hip_bf16.h>
#include <stdint.h>

#define LVLS 16
#define TSZ  524288          // hash table size per level (2^19)
#define TMASK 0x7FFFFu
#define NPTS 524288
#define P1 2654435761u
#define P2 805459861u
#define P3 3674653429u

// floor(16 * 1.5^l) computed in double, hardcoded
__constant__ float RES_TAB[16] = {
    16.f, 24.f, 36.f, 54.f, 81.f, 121.f, 182.f, 273.f,
    410.f, 615.f, 922.f, 1383.f, 2075.f, 3113.f, 4670.f, 7006.f};

using f16x8 = __attribute__((ext_vector_type(8))) _Float16;
using f32x4 = __attribute__((ext_vector_type(4))) float;

union PackF16 { uint32_t u; _Float16 h[2]; };

// ---------------------------------------------------------------------------
// Kernel W: swizzle all weight matrices (fp32 row-major [K][N]) into f16
// B-fragment layout for mfma_f32_16x16x32_f16:
//   dst[((ct*KC + kc)*64 + lane)*8 + j] = W[kc*32 + (lane>>4)*8 + j][ct*16 + (lane&15)]
// ---------------------------------------------------------------------------
struct WPtrs { const float* p[11]; };

__global__ void k_weights(WPtrs wp, _Float16* __restrict__ dst) {
    int id = blockIdx.x * 256 + threadIdx.x;
    if (id >= 69632) return;
    const int OFF[16] = {0,2048,6144,10240,14336,18432,20480,24576,28672,
                         32768,36864,45056,49152,57344,65536,69632};
    const int KK[15]  = {32,64,64,64,64,32,64,64,64,64,128,64,64,128,64};
    const int NN[15]  = {64,64,64,64,64,64,64,64,64,64,64,64,128,64,64};
    const int PSEL[15]= {0,1,1,1,2,3,4,4,4,5,6,7,8,9,10};
    const int POFF[15]= {0,0,4096,8192,0,0,0,4096,8192,0,0,0,0,0,0};
    int m = 0;
    while (id >= OFF[m+1]) m++;
    int local = id - OFF[m];
    int j    = local & 7;
    int lane = (local >> 3) & 63;
    int blk  = local >> 9;
    int KC   = KK[m] >> 5;
    int ct   = blk / KC;
    int kc   = blk - ct * KC;
    int k    = kc*32 + ((lane>>4)<<3) + j;
    int n    = ct*16 + (lane & 15);
    const float* src = wp.p[PSEL[m]] + POFF[m];
    dst[id] = (_Float16)src[k * NN[m] + n];
}

// ---------------------------------------------------------------------------
// Kernel T: fp32 tables -> packed 2xf16. Static = plain convert. Dynamic =
// t-blended: Td[l][i] = (1-ft)*table_d[l][i] + ft*table_d[l][i ^ cl],
// cl = (hash(p0t) ^ hash(p0t+1)) & TMASK  (per-level constant).
// ---------------------------------------------------------------------------
__global__ void k_tables(const float* __restrict__ ts, const float* __restrict__ td,
                         const float* __restrict__ tptr,
                         uint32_t* __restrict__ Ts16, uint32_t* __restrict__ Td16) {
    int id = blockIdx.x * 256 + threadIdx.x;
    PackF16 o;
    if (id < LVLS * TSZ) {
        float2 v = ((const float2*)ts)[id];
        o.h[0] = (_Float16)v.x; o.h[1] = (_Float16)v.y;
        Ts16[id] = o.u;
    } else {
        int d = id - LVLS * TSZ;
        if (d >= LVLS * TSZ) return;
        int lvl = d >> 19;
        int i   = d & TMASK;
        float res = RES_TAB[lvl];
        float tv  = tptr[0];
        float pt  = tv * res;
        float fpt = floorf(pt);
        float ft  = pt - fpt;
        uint32_t ut = (uint32_t)(int)fpt;
        uint32_t cl = ((ut * P3) ^ ((ut + 1u) * P3)) & TMASK;
        const float2* base = (const float2*)td + (size_t)lvl * TSZ;
        float2 a = base[i];
        float2 b = base[i ^ cl];
        o.h[0] = (_Float16)((1.f - ft) * a.x + ft * b.x);
        o.h[1] = (_Float16)((1.f - ft) * a.y + ft * b.y);
        Td16[d] = o.u;
    }
}

// ---------------------------------------------------------------------------
// Kernel E: hash-grid encode, level-major in lockstep for L2 locality.
// Grid = 1024 blocks (machine-filling, co-resident); each thread owns 2 points
// and loops levels 0..15, so the live table working set is ~1-2 level pairs
// (4-8 MB) per XCD L2. One xyz-hash serves both static and blended-dynamic
// tables (same primes): 16 gathers per (point, level).
// ---------------------------------------------------------------------------
__launch_bounds__(256)
__global__ void k_encode(const float* __restrict__ x, const float* __restrict__ tptr,
                         const uint32_t* __restrict__ Ts16, const uint32_t* __restrict__ Td16,
                         uint32_t* __restrict__ EncS, uint32_t* __restrict__ EncD) {
    int tid = threadIdx.x;
    int pbase = blockIdx.x * 512 + tid;
    float tv = tptr[0];
    float xs[2][3];
#pragma unroll
    for (int q = 0; q < 2; q++) {
        int p = pbase + q * 256;
        xs[q][0] = x[p*3]; xs[q][1] = x[p*3+1]; xs[q][2] = x[p*3+2];
    }
    for (int l = 0; l < LVLS; l++) {
        float res = RES_TAB[l];
        float pt  = tv * res;
        uint32_t ut = (uint32_t)(int)floorf(pt);
        uint32_t h0m = (ut * P3) & TMASK;
        const uint32_t* tsl = Ts16 + (size_t)l * TSZ;
        const uint32_t* tdl = Td16 + (size_t)l * TSZ;
#pragma unroll
        for (int q = 0; q < 2; q++) {
            int p = pbase + q * 256;
            float px = xs[q][0]*res, py = xs[q][1]*res, pz = xs[q][2]*res;
            float fx = floorf(px), fy = floorf(py), fz = floorf(pz);
            float wx1 = px-fx, wy1 = py-fy, wz1 = pz-fz;
            uint32_t ux = (uint32_t)(int)fx, uy = (uint32_t)(int)fy, uz = (uint32_t)(int)fz;
            uint32_t hx[2] = {ux, ux + 1u};
            uint32_t hy[2] = {uy * P1, (uy + 1u) * P1};
            uint32_t hz[2] = {uz * P2, (uz + 1u) * P2};
            float wxa[2] = {1.f - wx1, wx1};
            float wya[2] = {1.f - wy1, wy1};
            float wza[2] = {1.f - wz1, wz1};
            float sA0 = 0.f, sA1 = 0.f, sD0 = 0.f, sD1 = 0.f;
#pragma unroll
            for (int c = 0; c < 8; c++) {
                int cx = c & 1, cy = (c >> 1) & 1, cz = c >> 2;
                uint32_t idx = (hx[cx] ^ hy[cy] ^ hz[cz]) & TMASK;
                float w = wxa[cx] * wya[cy] * wza[cz];
                PackF16 s, d;
                s.u = tsl[idx];
                d.u = tdl[idx ^ h0m];
                sA0 += w * (float)s.h[0]; sA1 += w * (float)s.h[1];
                sD0 += w * (float)d.h[0]; sD1 += w * (float)d.h[1];
            }
            PackF16 o;
            o.h[0] = (_Float16)sA0; o.h[1] = (_Float16)sA1;
            EncS[(size_t)l * NPTS + p] = o.u;
            o.h[0] = (_Float16)sD0; o.h[1] = (_Float16)sD1;
            EncD[(size_t)l * NPTS + p] = o.u;
        }
    }
}

// ---------------------------------------------------------------------------
// Kernel M: full MLP pipeline for a 64-point tile. 4 waves; wave w owns output
// col-tiles w, w+4, ... All matmuls via mfma_f32_16x16x32_f16, fp32 accum.
// Fragment maps (gfx950): A[m=lane&15][k=(lane>>4)*8+j], B[k][n=lane&15],
// D row=(lane>>4)*4+i, col=lane&15.
// ---------------------------------------------------------------------------
template<int K, int NOUT, bool RELU>
__device__ __forceinline__ void layer_mm(const _Float16* A, int PA,
                                         const f16x8* __restrict__ Wf,
                                         _Float16* O, int PO,
                                         int wave, int lane) {
    constexpr int KC = K / 32;
    constexpr int NT = NOUT / 16;
    int m = lane & 15, quad = lane >> 4;
    for (int ct = wave; ct < NT; ct += 4) {
#pragma unroll
        for (int rt = 0; rt < 4; rt++) {
            f32x4 acc = {0.f, 0.f, 0.f, 0.f};
#pragma unroll
            for (int kc = 0; kc < KC; kc++) {
                f16x8 a = *(const f16x8*)(A + (rt*16 + m) * PA + kc*32 + quad*8);
                f16x8 b = Wf[(ct*KC + kc)*64 + lane];
                acc = __builtin_amdgcn_mfma_f32_16x16x32_f16(a, b, acc, 0, 0, 0);
            }
#pragma unroll
            for (int i = 0; i < 4; i++) {
                float v = acc[i];
                if (RELU) v = fmaxf(v, 0.f);
                O[(rt*16 + quad*4 + i) * PO + ct*16 + m] = (_Float16)v;
            }
        }
    }
}

// out1 layer fused with skip blend: F <- alpha*(A@W) + (1-alpha)*F, in place.
template<int K, int NOUT>
__device__ __forceinline__ void layer_blend(const _Float16* A, int PA,
                                            const f16x8* __restrict__ Wf,
                                            _Float16* F, int PF, float alpha,
                                            int wave, int lane) {
    constexpr int KC = K / 32;
    constexpr int NT = NOUT / 16;
    int m = lane & 15, quad = lane >> 4;
    for (int ct = wave; ct < NT; ct += 4) {
#pragma unroll
        for (int rt = 0; rt < 4; rt++) {
            f32x4 acc = {0.f, 0.f, 0.f, 0.f};
#pragma unroll
            for (int kc = 0; kc < KC; kc++) {
                f16x8 a = *(const f16x8*)(A + (rt*16 + m) * PA + kc*32 + quad*8);
                f16x8 b = Wf[(ct*KC + kc)*64 + lane];
                acc = __builtin_amdgcn_mfma_f32_16x16x32_f16(a, b, acc, 0, 0, 0);
            }
#pragma unroll
            for (int i = 0; i < 4; i++) {
                int ofs = (rt*16 + quad*4 + i) * PF + ct*16 + m;
                float f = (float)F[ofs];
                F[ofs] = (_Float16)(alpha * acc[i] + (1.f - alpha) * f);
            }
        }
    }
}

__launch_bounds__(256)
__global__ void k_mlp(const uint32_t* __restrict__ EncS, const uint32_t* __restrict__ EncD,
                      const _Float16* __restrict__ Wfrag, const float* __restrict__ alphap,
                      const float* __restrict__ w2out, float* __restrict__ out) {
    __shared__ _Float16 bufE [64 * 40];
    __shared__ _Float16 bufE2[64 * 40];
    __shared__ _Float16 bufA [64 * 72];
    __shared__ _Float16 bufB [64 * 72];
    __shared__ _Float16 bufF [64 * 136];
    int tid  = threadIdx.x;
    int base = blockIdx.x * 64;
    int wave = tid >> 6, lane = tid & 63;

    // stage encodings (level-major global layout -> row-major LDS tiles)
    for (int k = tid; k < 64 * 16; k += 256) {
        int l = k >> 6, r = k & 63;
        ((uint32_t*)bufE )[r*20 + l] = EncS[(size_t)l * NPTS + base + r];
        ((uint32_t*)bufE2)[r*20 + l] = EncD[(size_t)l * NPTS + base + r];
    }
    __syncthreads();

    const f16x8* W8 = (const f16x8*)Wfrag;
    // static MLP: 32->64, 3x 64->64 (relu), 64->64 linear -> bufF cols 0..63
    layer_mm<32, 64, true >(bufE,  40, W8 + 0,    bufA, 72, wave, lane); __syncthreads();
    layer_mm<64, 64, true >(bufA,  72, W8 + 256,  bufB, 72, wave, lane); __syncthreads();
    layer_mm<64, 64, true >(bufB,  72, W8 + 768,  bufA, 72, wave, lane); __syncthreads();
    layer_mm<64, 64, true >(bufA,  72, W8 + 1280, bufB, 72, wave, lane); __syncthreads();
    layer_mm<64, 64, false>(bufB,  72, W8 + 1792, bufF, 136, wave, lane); __syncthreads();
    // dynamic MLP -> bufF cols 64..127
    layer_mm<32, 64, true >(bufE2, 40, W8 + 2304, bufA, 72, wave, lane); __syncthreads();
    layer_mm<64, 64, true >(bufA,  72, W8 + 2560, bufB, 72, wave, lane); __syncthreads();
    layer_mm<64, 64, true >(bufB,  72, W8 + 3072, bufA, 72, wave, lane); __syncthreads();
    layer_mm<64, 64, true >(bufA,  72, W8 + 3584, bufB, 72, wave, lane); __syncthreads();
    layer_mm<64, 64, false>(bufB,  72, W8 + 4096, bufF + 64, 136, wave, lane); __syncthreads();
    // mlp1: 128->64, 64->64 (relu), 64->128 linear fused with skip blend
    layer_mm<128, 64, true>(bufF, 136, W8 + 4608, bufA, 72, wave, lane); __syncthreads();
    layer_mm<64,  64, true>(bufA,  72, W8 + 5632, bufB, 72, wave, lane); __syncthreads();
    float alpha = alphap[0];
    layer_blend<64, 128>(bufB, 72, W8 + 6144, bufF, 136, alpha, wave, lane); __syncthreads();
    // mlp2: 128->64, 64->64 (relu), then 64->1 in fp32
    layer_mm<128, 64, true>(bufF, 136, W8 + 7168, bufA, 72, wave, lane); __syncthreads();
    layer_mm<64,  64, true>(bufA,  72, W8 + 8192, bufB, 72, wave, lane); __syncthreads();

    if (tid < 64) {
        float acc = 0.f;
#pragma unroll
        for (int k2 = 0; k2 < 64; k2++)
            acc += (float)bufB[tid*72 + k2] * w2out[k2];
        out[base + tid] = acc;
    }
}

// ---------------------------------------------------------------------------
extern "C" void kernel_launch(void* const* d_in, const int* in_sizes, int n_in,
                              void* d_out, int out_size, void* d_ws, size_t ws_size,
                              hipStream_t stream) {
    const float* x      = (const float*)d_in[0];
    const float* t      = (const float*)d_in[1];
    const float* alpha  = (const float*)d_in[2];
    const float* tab_s  = (const float*)d_in[3];
    const float* ws_in  = (const float*)d_in[4];
    const float* ws_hid = (const float*)d_in[5];
    const float* ws_out = (const float*)d_in[6];
    const float* tab_d  = (const float*)d_in[7];
    const float* wd_in  = (const float*)d_in[8];
    const float* wd_hid = (const float*)d_in[9];
    const float* wd_out = (const float*)d_in[10];
    const float* w1_in  = (const float*)d_in[11];
    const float* w1_hid = (const float*)d_in[12];
    const float* w1_out = (const float*)d_in[13];
    const float* w2_in  = (const float*)d_in[14];
    const float* w2_hid = (const float*)d_in[15];
    const float* w2_out = (const float*)d_in[16];
    float* out = (float*)d_out;

    char* ws = (char*)d_ws;
    _Float16* Wfrag = (_Float16*)ws;                       // 139264 B
    uint32_t* Ts16  = (uint32_t*)(ws + 139264);            // 32 MiB
    uint32_t* Td16  = Ts16 + (size_t)LVLS * TSZ;           // 32 MiB
    uint32_t* EncS  = Td16 + (size_t)LVLS * TSZ;           // 32 MiB
    uint32_t* EncD  = EncS + (size_t)LVLS * NPTS;          // 32 MiB
    size_t needed = 139264 + 4ull * (size_t)LVLS * TSZ * 4ull;
    if (ws_size < needed) return;  // ws too small: leaves output zero (diagnosable)

    WPtrs wp;
    wp.p[0] = ws_in;  wp.p[1] = ws_hid; wp.p[2] = ws_out;
    wp.p[3] = wd_in;  wp.p[4] = wd_hid; wp.p[5] = wd_out;
    wp.p[6] = w1_in;  wp.p[7] = w1_hid; wp.p[8] = w1_out;
    wp.p[9] = w2_in;  wp.p[10] = w2_hid;

    k_weights<<<272, 256, 0, stream>>>(wp, Wfrag);
    k_tables<<<65536, 256, 0, stream>>>(tab_s, tab_d, t, Ts16, Td16);
    k_encode<<<1024, 256, 0, stream>>>(x, t, Ts16, Td16, EncS, EncD);
    k_mlp<<<NPTS / 64, 256, 0, stream>>>(EncS, EncD, Wfrag, alpha, w2_out, out);
}

// Round 2
// 639.051 us; speedup vs baseline: 1.5348x; 1.5348x over previous
//
#include <hip/hip_runtime.h>
#include <hip/hip_bf16.h>
#include <stdint.h>

#define LVLS 16
#define TSZ  524288          // hash table size per level (2^19)
#define TMASK 0x7FFFFu
#define NPTS 524288
#define P1 2654435761u
#define P2 805459861u
#define P3 3674653429u

// floor(16 * 1.5^l), hardcoded
__constant__ float RES_TAB[16] = {
    16.f, 24.f, 36.f, 54.f, 81.f, 121.f, 182.f, 273.f,
    410.f, 615.f, 922.f, 1383.f, 2075.f, 3113.f, 4670.f, 7006.f};

using f16x8 = __attribute__((ext_vector_type(8))) _Float16;
using f32x4 = __attribute__((ext_vector_type(4))) float;

union PackF16 { uint32_t u; _Float16 h[2]; };

constexpr int PC = 136;   // padded LDS row pitch (f16) — breaks 8-way bank conflict

// ---------------------------------------------------------------------------
// Kernel W: swizzle weights (fp32 [K][N] row-major) into f16 B-fragment layout
// for mfma_f32_16x16x32_f16 (verified in round 1):
//   dst[((ct*KC+kc)*64+lane)*8+j] = W[kc*32+(lane>>4)*8+j][ct*16+(lane&15)]
// ---------------------------------------------------------------------------
struct WPtrs { const float* p[11]; };

__global__ void k_weights(WPtrs wp, _Float16* __restrict__ dst) {
    int id = blockIdx.x * 256 + threadIdx.x;
    if (id >= 69632) return;
    const int OFF[16] = {0,2048,6144,10240,14336,18432,20480,24576,28672,
                         32768,36864,45056,49152,57344,65536,69632};
    const int KK[15]  = {32,64,64,64,64,32,64,64,64,64,128,64,64,128,64};
    const int NN[15]  = {64,64,64,64,64,64,64,64,64,64,64,64,128,64,64};
    const int PSEL[15]= {0,1,1,1,2,3,4,4,4,5,6,7,8,9,10};
    const int POFF[15]= {0,0,4096,8192,0,0,0,4096,8192,0,0,0,0,0,0};
    int m = 0;
    while (id >= OFF[m+1]) m++;
    int local = id - OFF[m];
    int j    = local & 7;
    int lane = (local >> 3) & 63;
    int blk  = local >> 9;
    int KC   = KK[m] >> 5;
    int ct   = blk / KC;
    int kc   = blk - ct * KC;
    int k    = kc*32 + ((lane>>4)<<3) + j;
    int n    = ct*16 + (lane & 15);
    const float* src = wp.p[PSEL[m]] + POFF[m];
    dst[id] = (_Float16)src[k * NN[m] + n];
}

// ---------------------------------------------------------------------------
// Kernel T: build COMBINED f16 table. Tc[l][i] = { static(i), dynamic(i) }:
//   static  = ts[l][i]
//   dynamic = (1-ft)*td[l][i^h0] + ft*td[l][i^h1],
//             h0=(ut*P3)&TMASK, h1=((ut+1)*P3)&TMASK  (t-corner hashes baked in)
// so the encode kernel needs ONE index per corner for both features.
// ---------------------------------------------------------------------------
__global__ void k_tables(const float* __restrict__ ts, const float* __restrict__ td,
                         const float* __restrict__ tptr, uint2* __restrict__ Tc) {
    int id = blockIdx.x * 256 + threadIdx.x;   // 0 .. LVLS*TSZ-1
    int l = id >> 19, i = id & TMASK;
    float2 sv = ((const float2*)ts)[id];
    float res = RES_TAB[l];
    float tv  = tptr[0];
    float pt  = tv * res;
    float fpt = floorf(pt);
    float ft  = pt - fpt;
    uint32_t ut = (uint32_t)(int)fpt;
    uint32_t h0 = (ut * P3) & TMASK;
    uint32_t h1 = ((ut + 1u) * P3) & TMASK;
    const float2* tdl = (const float2*)td + (size_t)l * TSZ;
    float2 a = tdl[i ^ h0];
    float2 b = tdl[i ^ h1];
    PackF16 o0, o1;
    o0.h[0] = (_Float16)sv.x; o0.h[1] = (_Float16)sv.y;
    o1.h[0] = (_Float16)((1.f - ft) * a.x + ft * b.x);
    o1.h[1] = (_Float16)((1.f - ft) * a.y + ft * b.y);
    Tc[id] = make_uint2(o0.u, o1.u);
}

// ---------------------------------------------------------------------------
// Kernel E: hash-grid encode, level-per-XCD sharded. Blocks with
// blockIdx%8==c handle levels 2c, 2c+1 for ALL points -> each XCD's live
// table slice is one 4 MiB level, resident in its private L2.
// 8 x 8-byte gathers per (point, level) serve both static and dynamic.
// ---------------------------------------------------------------------------
__launch_bounds__(256)
__global__ void k_encode(const float* __restrict__ x,
                         const uint2* __restrict__ Tc,
                         uint32_t* __restrict__ EncS, uint32_t* __restrict__ EncD) {
    int tid  = threadIdx.x;
    int xcd  = blockIdx.x & 7;
    int slot = blockIdx.x >> 3;          // 0..255
    int gt   = slot * 256 + tid;         // 0..65535 within the xcd class
#pragma unroll
    for (int pass = 0; pass < 2; pass++) {
        int l = xcd * 2 + pass;
        float res = RES_TAB[l];
        const uint2* tcl = Tc + (size_t)l * TSZ;
        uint32_t* es = EncS + (size_t)l * NPTS;
        uint32_t* ed = EncD + (size_t)l * NPTS;
        for (int q = 0; q < 8; q++) {
            int p = gt + q * 65536;
            float px = x[p*3+0]*res, py = x[p*3+1]*res, pz = x[p*3+2]*res;
            float fx = floorf(px), fy = floorf(py), fz = floorf(pz);
            float wx = px-fx, wy = py-fy, wz = pz-fz;
            uint32_t ux = (uint32_t)(int)fx, uy = (uint32_t)(int)fy, uz = (uint32_t)(int)fz;
            uint32_t hx[2] = {ux, ux + 1u};
            uint32_t hy[2] = {uy * P1, (uy + 1u) * P1};
            uint32_t hz[2] = {uz * P2, (uz + 1u) * P2};
            uint2 v[8];
#pragma unroll
            for (int c = 0; c < 8; c++) {
                uint32_t idx = (hx[c&1] ^ hy[(c>>1)&1] ^ hz[c>>2]) & TMASK;
                v[c] = tcl[idx];
            }
            float wxa[2] = {1.f - wx, wx};
            float wya[2] = {1.f - wy, wy};
            float wza[2] = {1.f - wz, wz};
            float sA0 = 0.f, sA1 = 0.f, sD0 = 0.f, sD1 = 0.f;
#pragma unroll
            for (int c = 0; c < 8; c++) {
                float w = wxa[c&1] * wya[(c>>1)&1] * wza[c>>2];
                PackF16 s, d; s.u = v[c].x; d.u = v[c].y;
                sA0 += w * (float)s.h[0]; sA1 += w * (float)s.h[1];
                sD0 += w * (float)d.h[0]; sD1 += w * (float)d.h[1];
            }
            PackF16 o;
            o.h[0] = (_Float16)sA0; o.h[1] = (_Float16)sA1; es[p] = o.u;
            o.h[0] = (_Float16)sD0; o.h[1] = (_Float16)sD1; ed[p] = o.u;
        }
    }
}

// ---------------------------------------------------------------------------
// Kernel M: barrier-free MLP. Each WAVE owns 16 points and runs all layers
// privately; layer transposes go through a per-wave LDS scratch ordered by
// in-wave lgkmcnt only (DS ops are in-order per wave). No __syncthreads().
// Fragment maps: A[m=lane&15][k=quad*8+j], B frag from k_weights,
// D row=quad*4+i, col=lane&15.
// ---------------------------------------------------------------------------
__device__ __forceinline__ void wait_lds() {
    asm volatile("s_waitcnt lgkmcnt(0)" ::: "memory");
}

// MFMA over NT=4 col-tiles, optional relu, write D (f16) into per-wave LDS buf
template<int KC, bool RELU>
__device__ __forceinline__ void mm_to_lds(const f16x8* a, const f16x8* __restrict__ W,
                                          _Float16* buf, int m, int quad, int lane) {
#pragma unroll
    for (int ct = 0; ct < 4; ct++) {
        f32x4 acc = {0.f, 0.f, 0.f, 0.f};
#pragma unroll
        for (int kc = 0; kc < KC; kc++)
            acc = __builtin_amdgcn_mfma_f32_16x16x32_f16(a[kc], W[(ct*KC+kc)*64+lane], acc, 0, 0, 0);
#pragma unroll
        for (int i = 0; i < 4; i++) {
            float v = acc[i];
            if (RELU) v = fmaxf(v, 0.f);
            buf[(quad*4+i)*PC + ct*16 + m] = (_Float16)v;
        }
    }
}

// Linear-out layer: write D to buf AND keep packed copy in regs (for blend)
template<int KC>
__device__ __forceinline__ void mm_keep(const f16x8* a, const f16x8* __restrict__ W,
                                        _Float16* buf, PackF16* P, int m, int quad, int lane) {
#pragma unroll
    for (int ct = 0; ct < 4; ct++) {
        f32x4 acc = {0.f, 0.f, 0.f, 0.f};
#pragma unroll
        for (int kc = 0; kc < KC; kc++)
            acc = __builtin_amdgcn_mfma_f32_16x16x32_f16(a[kc], W[(ct*KC+kc)*64+lane], acc, 0, 0, 0);
#pragma unroll
        for (int ih = 0; ih < 2; ih++) {
            PackF16 pk;
            pk.h[0] = (_Float16)acc[ih*2+0];
            pk.h[1] = (_Float16)acc[ih*2+1];
            P[ct*2+ih] = pk;
            buf[(quad*4+ih*2+0)*PC + ct*16 + m] = pk.h[0];
            buf[(quad*4+ih*2+1)*PC + ct*16 + m] = pk.h[1];
        }
    }
}

template<int KC>
__device__ __forceinline__ void lds_to_afrag(const _Float16* buf, f16x8* a, int m, int quad) {
#pragma unroll
    for (int kc = 0; kc < KC; kc++)
        a[kc] = *(const f16x8*)(buf + m*PC + kc*32 + quad*8);
}

__device__ __forceinline__ void load_enc(const uint32_t* __restrict__ Enc,
                                         int pbase, int m, int quad, f16x8* a) {
    union { uint32_t u[4]; f16x8 v; } cv;
#pragma unroll
    for (int jj = 0; jj < 4; jj++)
        cv.u[jj] = Enc[(size_t)(quad*4+jj) * NPTS + pbase + m];
    a[0] = cv.v;
}

__launch_bounds__(256)
__global__ void k_mlp(const uint32_t* __restrict__ EncS, const uint32_t* __restrict__ EncD,
                      const _Float16* __restrict__ Wfrag, const float* __restrict__ alphap,
                      const float* __restrict__ w2out, float* __restrict__ out) {
    __shared__ _Float16 Sbuf[4][16*PC];
    __shared__ _Float16 Fbuf[4][16*PC];
    int tid  = threadIdx.x;
    int wave = tid >> 6, lane = tid & 63;
    int m = lane & 15, quad = lane >> 4;
    int pbase = blockIdx.x * 64 + wave * 16;
    _Float16* S = Sbuf[wave];
    _Float16* F = Fbuf[wave];
    const f16x8* W8 = (const f16x8*)Wfrag;

    f16x8 a[4];
    PackF16 sP[8], dP[8];

    // ---- static encoder MLP -> F cols 0..63 (+ regs) ----
    load_enc(EncS, pbase, m, quad, a);
    mm_to_lds<1, true>(a, W8 + 0,    S, m, quad, lane); wait_lds();
    lds_to_afrag<2>(S, a, m, quad);
    mm_to_lds<2, true>(a, W8 + 256,  S, m, quad, lane); wait_lds();
    lds_to_afrag<2>(S, a, m, quad);
    mm_to_lds<2, true>(a, W8 + 768,  S, m, quad, lane); wait_lds();
    lds_to_afrag<2>(S, a, m, quad);
    mm_to_lds<2, true>(a, W8 + 1280, S, m, quad, lane); wait_lds();
    lds_to_afrag<2>(S, a, m, quad);
    mm_keep<2>(a, W8 + 1792, F, sP, m, quad, lane);
    // ---- dynamic encoder MLP -> F cols 64..127 (+ regs) ----
    load_enc(EncD, pbase, m, quad, a);
    mm_to_lds<1, true>(a, W8 + 2304, S, m, quad, lane); wait_lds();
    lds_to_afrag<2>(S, a, m, quad);
    mm_to_lds<2, true>(a, W8 + 2560, S, m, quad, lane); wait_lds();
    lds_to_afrag<2>(S, a, m, quad);
    mm_to_lds<2, true>(a, W8 + 3072, S, m, quad, lane); wait_lds();
    lds_to_afrag<2>(S, a, m, quad);
    mm_to_lds<2, true>(a, W8 + 3584, S, m, quad, lane); wait_lds();
    lds_to_afrag<2>(S, a, m, quad);
    mm_keep<2>(a, W8 + 4096, F + 64, dP, m, quad, lane);
    wait_lds();
    // ---- mlp1: 128->64 relu, 64->64 relu ----
    lds_to_afrag<4>(F, a, m, quad);
    mm_to_lds<4, true>(a, W8 + 4608, S, m, quad, lane); wait_lds();
    lds_to_afrag<2>(S, a, m, quad);
    mm_to_lds<2, true>(a, W8 + 5632, S, m, quad, lane); wait_lds();
    lds_to_afrag<2>(S, a, m, quad);
    // ---- out1 (64->128) fused with skip blend, write F in place ----
    float alpha = alphap[0];
#pragma unroll
    for (int ct = 0; ct < 8; ct++) {
        f32x4 acc = {0.f, 0.f, 0.f, 0.f};
#pragma unroll
        for (int kc = 0; kc < 2; kc++)
            acc = __builtin_amdgcn_mfma_f32_16x16x32_f16(a[kc], W8[6144 + (ct*2+kc)*64+lane], acc, 0, 0, 0);
#pragma unroll
        for (int i = 0; i < 4; i++) {
            float f = (ct < 4) ? (float)sP[ct*2 + (i>>1)].h[i&1]
                               : (float)dP[(ct-4)*2 + (i>>1)].h[i&1];
            F[(quad*4+i)*PC + ct*16 + m] = (_Float16)(alpha * acc[i] + (1.f - alpha) * f);
        }
    }
    wait_lds();
    // ---- mlp2: 128->64 relu, 64->64 relu, dot w2_out ----
    lds_to_afrag<4>(F, a, m, quad);
    mm_to_lds<4, true>(a, W8 + 7168, S, m, quad, lane); wait_lds();
    lds_to_afrag<2>(S, a, m, quad);
    float rsum[4] = {0.f, 0.f, 0.f, 0.f};
#pragma unroll
    for (int ct = 0; ct < 4; ct++) {
        f32x4 acc = {0.f, 0.f, 0.f, 0.f};
#pragma unroll
        for (int kc = 0; kc < 2; kc++)
            acc = __builtin_amdgcn_mfma_f32_16x16x32_f16(a[kc], W8[8192 + (ct*2+kc)*64+lane], acc, 0, 0, 0);
        float wv = w2out[ct*16 + m];
#pragma unroll
        for (int i = 0; i < 4; i++)
            rsum[i] += fmaxf(acc[i], 0.f) * wv;
    }
#pragma unroll
    for (int off = 1; off < 16; off <<= 1) {
#pragma unroll
        for (int i = 0; i < 4; i++)
            rsum[i] += __shfl_xor(rsum[i], off, 64);
    }
    if (m == 0) {
#pragma unroll
        for (int i = 0; i < 4; i++)
            out[pbase + quad*4 + i] = rsum[i];
    }
}

// ---------------------------------------------------------------------------
extern "C" void kernel_launch(void* const* d_in, const int* in_sizes, int n_in,
                              void* d_out, int out_size, void* d_ws, size_t ws_size,
                              hipStream_t stream) {
    const float* x      = (const float*)d_in[0];
    const float* t      = (const float*)d_in[1];
    const float* alpha  = (const float*)d_in[2];
    const float* tab_s  = (const float*)d_in[3];
    const float* ws_in  = (const float*)d_in[4];
    const float* ws_hid = (const float*)d_in[5];
    const float* ws_out = (const float*)d_in[6];
    const float* tab_d  = (const float*)d_in[7];
    const float* wd_in  = (const float*)d_in[8];
    const float* wd_hid = (const float*)d_in[9];
    const float* wd_out = (const float*)d_in[10];
    const float* w1_in  = (const float*)d_in[11];
    const float* w1_hid = (const float*)d_in[12];
    const float* w1_out = (const float*)d_in[13];
    const float* w2_in  = (const float*)d_in[14];
    const float* w2_hid = (const float*)d_in[15];
    const float* w2_out = (const float*)d_in[16];
    float* out = (float*)d_out;

    char* ws = (char*)d_ws;
    _Float16* Wfrag = (_Float16*)ws;                       // 139264 B
    uint2*    Tc    = (uint2*)(ws + 139264);               // 64 MiB combined table
    uint32_t* EncS  = (uint32_t*)(ws + 139264 + 67108864); // 32 MiB
    uint32_t* EncD  = EncS + (size_t)LVLS * NPTS;          // 32 MiB
    size_t needed = 139264 + 67108864 + 2ull * 33554432ull;
    if (ws_size < needed) return;

    WPtrs wp;
    wp.p[0] = ws_in;  wp.p[1] = ws_hid; wp.p[2] = ws_out;
    wp.p[3] = wd_in;  wp.p[4] = wd_hid; wp.p[5] = wd_out;
    wp.p[6] = w1_in;  wp.p[7] = w1_hid; wp.p[8] = w1_out;
    wp.p[9] = w2_in;  wp.p[10] = w2_hid;

    k_weights<<<272,   256, 0, stream>>>(wp, Wfrag);
    k_tables <<<32768, 256, 0, stream>>>(tab_s, tab_d, t, Tc);
    k_encode <<<2048,  256, 0, stream>>>(x, Tc, EncS, EncD);
    k_mlp    <<<NPTS/64, 256, 0, stream>>>(EncS, EncD, Wfrag, alpha, w2_out, out);
}